// Round 5
// baseline (329.236 us; speedup 1.0000x reference)
//
#include <hip/hip_runtime.h>
#include <hip/hip_fp16.h>

// Problem constants
#define NF 32
#define DM 256
#define HH 128
#define BB 16
#define TT 512
#define BT 8192            // B*T tokens
#define OUT_W_OFF 2097152  // B*T*D
#define EPS 1e-5f

typedef __bf16 bf16x8 __attribute__((ext_vector_type(8)));
typedef float  f32x16 __attribute__((ext_vector_type(16)));
typedef __fp16 f16x2 __attribute__((ext_vector_type(2)));
typedef __fp16 f16x8 __attribute__((ext_vector_type(8)));

__device__ __forceinline__ float eluf(float z){ return z > 0.f ? z : __expf(z) - 1.f; }
__device__ __forceinline__ float sigm(float z){ return 1.f/(1.f + __expf(-z)); }
__device__ __forceinline__ unsigned f2bf(float x){
  unsigned u = __float_as_uint(x);
  u += 0x7fffu + ((u>>16)&1u);   // RNE
  return u>>16;
}
__device__ __forceinline__ float rdlane(float v, int l){
  return __uint_as_float(__builtin_amdgcn_readlane(__float_as_uint(v), l));
}
// broadcast token-indexed value for MFMA C/D row r: m = (r&3)+8*(r>>2)+4*q
__device__ __forceinline__ float qsel(float v, int mb, int lane){
  float a0 = rdlane(v, mb), a1 = rdlane(v, mb+4);
  return (lane & 32) ? a1 : a0;
}

// ---------------- prep: repack w2/wg (f32) -> bf16 B-fragment layout ----------------
// Wpk[f][c][nt][ks][lane][j]: k=ks*16+(lane>>5)*8+j, d=c*32+(lane&31), nt0=proj nt1=gate
__global__ __launch_bounds__(256) void k_prep(const float* __restrict__ w2,
                                              const float* __restrict__ wgm,
                                              uint4* __restrict__ Wpk){
  __shared__ float ssrc[2][128][32];
  const int tid = threadIdx.x;
  const int f = blockIdx.x, c = blockIdx.y;
  #pragma unroll
  for (int it = 0; it < 32; ++it){
    int idx = tid + it*256;
    int arr = idx >> 12;
    int rem = idx & 4095;
    int k = rem >> 5, dd = rem & 31;
    const float* src = arr ? wgm : w2;
    ssrc[arr][k][dd] = src[(f*HH + k)*DM + c*32 + dd];
  }
  __syncthreads();
  #pragma unroll
  for (int p = 0; p < 4; ++p){
    int oc = tid + p*256;
    int nt = oc>>9, ks = (oc>>6)&7, l = oc&63;
    int k0 = ks*16 + (l>>5)*8, dd = l&31;
    float v[8];
    #pragma unroll
    for (int j=0;j<8;++j) v[j] = ssrc[nt][k0+j][dd];
    uint4 pk;
    pk.x = f2bf(v[0]) | (f2bf(v[1])<<16);
    pk.y = f2bf(v[2]) | (f2bf(v[3])<<16);
    pk.z = f2bf(v[4]) | (f2bf(v[5])<<16);
    pk.w = f2bf(v[6]) | (f2bf(v[7])<<16);
    Wpk[(f*8 + c)*1024 + oc] = pk;
  }
}

// ---------------- pass1: GRN, raw s (fp16) -> global, mu/rs -> global, pooled ----------------
// No A LDS (frags computed per-lane), no stage. stk layout:
// u4 idx = f*262144 + blk*4096 + c*512 + wid*128 + q*64 + col*2 + half ; fp16[j] = row r=half*8+j
__global__ __launch_bounds__(256) void k_pass1(
    const float* __restrict__ x,  const float* __restrict__ w1, const float* __restrict__ b1,
    const float* __restrict__ b2, const float* __restrict__ bg,
    const float* __restrict__ wsk, const float* __restrict__ bsk,
    const float* __restrict__ lng, const float* __restrict__ lnb,
    const uint4* __restrict__ Wpk,
    float* __restrict__ muw, float* __restrict__ rsw,
    float* __restrict__ pooled, uint4* __restrict__ stk4){
  __shared__ float poolbuf[256];
  __shared__ float Cbuf;
  const int tid = threadIdx.x, lane = tid&63, wid = tid>>6;
  const int col = lane&31, q = lane>>5;
  const int f = blockIdx.y;
  const int tok0 = blockIdx.x*128;
  const int b = tok0 >> 9;
  poolbuf[tid] = 0.f;
  if (tid == 0) Cbuf = 0.f;
  __syncthreads();
  const float xl = x[(tok0 + wid*32 + col)*NF + f];
  // A fragments computed directly in registers (m=col token, k=ks*16+q*8+j)
  bf16x8 afr[8];
  {
    const float* wp = w1 + f*HH + q*8;
    const float* bp = b1 + f*HH + q*8;
    #pragma unroll
    for (int ks=0;ks<8;++ks){
      float4 wa = *(const float4*)(wp + ks*16);
      float4 wb = *(const float4*)(wp + ks*16 + 4);
      float4 ba = *(const float4*)(bp + ks*16);
      float4 bb = *(const float4*)(bp + ks*16 + 4);
      float h0 = eluf(fmaf(xl, wa.x, ba.x));
      float h1 = eluf(fmaf(xl, wa.y, ba.y));
      float h2 = eluf(fmaf(xl, wa.z, ba.z));
      float h3 = eluf(fmaf(xl, wa.w, ba.w));
      float h4 = eluf(fmaf(xl, wb.x, bb.x));
      float h5 = eluf(fmaf(xl, wb.y, bb.y));
      float h6 = eluf(fmaf(xl, wb.z, bb.z));
      float h7 = eluf(fmaf(xl, wb.w, bb.w));
      uint4 pk;
      pk.x = f2bf(h0) | (f2bf(h1)<<16);
      pk.y = f2bf(h2) | (f2bf(h3)<<16);
      pk.z = f2bf(h4) | (f2bf(h5)<<16);
      pk.w = f2bf(h6) | (f2bf(h7)<<16);
      afr[ks] = __builtin_bit_cast(bf16x8, pk);
    }
  }
  float xr[16];
  #pragma unroll
  for (int r=0;r<16;++r) xr[r] = qsel(xl, (r&3)+8*(r>>2), lane);
  float sum[16], ssq[16];
  #pragma unroll
  for (int r=0;r<16;++r){ sum[r]=0.f; ssq[r]=0.f; }
  const size_t sbase = (size_t)f*262144 + (size_t)blockIdx.x*4096
                     + (size_t)(wid*128 + q*64 + col*2);
  for (int c=0; c<8; ++c){
    const uint4* wb4 = Wpk + (f*8 + c)*1024;
    bf16x8 bf0[8], bf1[8];
    #pragma unroll
    for (int ks=0;ks<8;++ks) bf0[ks] = __builtin_bit_cast(bf16x8, wb4[ks*64 + lane]);
    #pragma unroll
    for (int ks=0;ks<8;++ks) bf1[ks] = __builtin_bit_cast(bf16x8, wb4[512 + ks*64 + lane]);
    f32x16 acc0 = {0.f}, acc1 = {0.f};
    #pragma unroll
    for (int ks=0;ks<8;++ks){
      acc0 = __builtin_amdgcn_mfma_f32_32x32x16_bf16(afr[ks], bf0[ks], acc0, 0,0,0);
      acc1 = __builtin_amdgcn_mfma_f32_32x32x16_bf16(afr[ks], bf1[ks], acc1, 0,0,0);
    }
    const int d = c*32 + col;
    const float b2v = b2[f*DM+d], bgv = bg[f*DM+d];
    const float wsv = wsk[f*DM+d], bsv = bsk[f*DM+d];
    unsigned pk[8];
    #pragma unroll
    for (int i=0;i<8;++i){
      const int r0 = 2*i, r1 = 2*i+1;
      float sv0 = fmaf(xr[r0], wsv, bsv) + sigm(acc1[r0]+bgv)*(acc0[r0]+b2v);
      float sv1 = fmaf(xr[r1], wsv, bsv) + sigm(acc1[r1]+bgv)*(acc0[r1]+b2v);
      sum[r0] += sv0; ssq[r0] = fmaf(sv0, sv0, ssq[r0]);
      sum[r1] += sv1; ssq[r1] = fmaf(sv1, sv1, ssq[r1]);
      pk[i] = __builtin_bit_cast(unsigned, __builtin_amdgcn_cvt_pkrtz(sv0, sv1));
    }
    uint4 u0, u1;
    u0.x = pk[0]; u0.y = pk[1]; u0.z = pk[2]; u0.w = pk[3];
    u1.x = pk[4]; u1.y = pk[5]; u1.z = pk[6]; u1.w = pk[7];
    stk4[sbase + c*512    ] = u0;
    stk4[sbase + c*512 + 1] = u1;
  }
  // LN stats: butterfly over 32 cols within each q-half
  #pragma unroll
  for (int r=0;r<16;++r){
    float s1 = sum[r], s2 = ssq[r];
    s1 += __shfl_xor(s1,1);  s2 += __shfl_xor(s2,1);
    s1 += __shfl_xor(s1,2);  s2 += __shfl_xor(s2,2);
    s1 += __shfl_xor(s1,4);  s2 += __shfl_xor(s2,4);
    s1 += __shfl_xor(s1,8);  s2 += __shfl_xor(s2,8);
    s1 += __shfl_xor(s1,16); s2 += __shfl_xor(s2,16);
    float mu = s1 * (1.f/256.f);
    float var = fmaf(-mu, mu, s2*(1.f/256.f));
    sum[r] = mu;
    ssq[r] = rsqrtf(fmaxf(var, 0.f) + EPS);
  }
  if (col == 0){
    const int tb = tok0 + wid*32 + 4*q;   // r=0..3 -> m=r+4q, contiguous float4 runs
    *(float4*)(muw + f*BT + tb)      = make_float4(sum[0],sum[1],sum[2],sum[3]);
    *(float4*)(muw + f*BT + tb + 8)  = make_float4(sum[4],sum[5],sum[6],sum[7]);
    *(float4*)(muw + f*BT + tb + 16) = make_float4(sum[8],sum[9],sum[10],sum[11]);
    *(float4*)(muw + f*BT + tb + 24) = make_float4(sum[12],sum[13],sum[14],sum[15]);
    *(float4*)(rsw + f*BT + tb)      = make_float4(ssq[0],ssq[1],ssq[2],ssq[3]);
    *(float4*)(rsw + f*BT + tb + 8)  = make_float4(ssq[4],ssq[5],ssq[6],ssq[7]);
    *(float4*)(rsw + f*BT + tb + 16) = make_float4(ssq[8],ssq[9],ssq[10],ssq[11]);
    *(float4*)(rsw + f*BT + tb + 24) = make_float4(ssq[12],ssq[13],ssq[14],ssq[15]);
  }
  // pooled via identity: sum_t shat = g*(sum_t s*rs - sum_t mu*rs) + 128*b (per block)
  float Cpart = 0.f;
  #pragma unroll
  for (int r=0;r<16;++r) Cpart = fmaf(sum[r], ssq[r], Cpart);
  #pragma unroll
  for (int c=0;c<8;++c){
    uint4 u0 = stk4[sbase + c*512];       // L2-hot re-read of own stores
    uint4 u1 = stk4[sbase + c*512 + 1];
    f16x8 a = __builtin_bit_cast(f16x8, u0);
    f16x8 g = __builtin_bit_cast(f16x8, u1);
    float A = 0.f;
    #pragma unroll
    for (int jj=0;jj<8;++jj) A = fmaf((float)a[jj], ssq[jj], A);
    #pragma unroll
    for (int jj=0;jj<8;++jj) A = fmaf((float)g[jj], ssq[8+jj], A);
    A += __shfl_xor(A, 32);
    if (q == 0) atomicAdd(&poolbuf[c*32 + col], A);
  }
  if (col == 0) atomicAdd(&Cbuf, Cpart);
  __syncthreads();
  const float contrib = fmaf(lng[f*DM+tid], poolbuf[tid] - Cbuf, 128.f*lnb[f*DM+tid]);
  atomicAdd(&pooled[b*8192 + f*DM + tid], contrib);
}

// ---------------- pass2a: flat_pooled @ W1 / @ Ws (split-K partials) ----------------
__global__ __launch_bounds__(256) void k_pass2a(const float* __restrict__ pooled,
    const float* __restrict__ W1, const float* __restrict__ Wsm,
    float* __restrict__ hw_pre, float* __restrict__ sk_pre){
  __shared__ float fl[512];
  const int tid = threadIdx.x;
  const int b = blockIdx.x;
  const int k0 = blockIdx.y * 512;
  fl[tid]       = pooled[b*8192 + k0 + tid]       * (1.f/512.f);
  fl[tid+256]   = pooled[b*8192 + k0 + tid + 256] * (1.f/512.f);
  __syncthreads();
  float acc = 0.f;
  const float* wcol = W1 + (size_t)k0*DM + tid;
  #pragma unroll 4
  for (int i=0;i<512;++i) acc = fmaf(fl[i], wcol[(size_t)i*DM], acc);
  atomicAdd(&hw_pre[b*DM + tid], acc);
  const int colj = tid & 31, sub = tid >> 5;
  float acc2 = 0.f;
  const float* wscol = Wsm + (size_t)(k0 + sub*64)*NF + colj;
  const float* fls = fl + sub*64;
  #pragma unroll 4
  for (int i=0;i<64;++i) acc2 = fmaf(fls[i], wscol[(size_t)i*NF], acc2);
  atomicAdd(&sk_pre[b*NF + colj], acc2);
}

// ---------------- pass2b: weight GRN + LN + softmax -> weights ----------------
__global__ __launch_bounds__(64) void k_pass2b(const float* __restrict__ hw_pre, const float* __restrict__ sk_pre,
    const float* __restrict__ B1, const float* __restrict__ W2, const float* __restrict__ B2,
    const float* __restrict__ Wg, const float* __restrict__ Bg, const float* __restrict__ Bs,
    const float* __restrict__ LNg, const float* __restrict__ LNb,
    float* __restrict__ out, float* __restrict__ wsel){
  __shared__ float hw[256];
  const int tid = threadIdx.x, b = blockIdx.x;
  for (int i=tid;i<256;i+=64) hw[i] = eluf(hw_pre[b*DM+i] + B1[i]);
  __syncthreads();
  if (tid < 32){
    const int j = tid;
    float ap = B2[j], ag = Bg[j];
    #pragma unroll 4
    for (int i=0;i<256;++i){ float h = hw[i]; ap = fmaf(h, W2[i*NF+j], ap); ag = fmaf(h, Wg[i*NF+j], ag); }
    float gw = sigm(ag);
    float v = sk_pre[b*NF+j] + Bs[j] + gw*ap;
    float s1 = v;
    s1 += __shfl_xor(s1,1); s1 += __shfl_xor(s1,2); s1 += __shfl_xor(s1,4); s1 += __shfl_xor(s1,8); s1 += __shfl_xor(s1,16);
    float mean = s1*(1.f/32.f);
    float dv = v - mean;
    float s2 = dv*dv;
    s2 += __shfl_xor(s2,1); s2 += __shfl_xor(s2,2); s2 += __shfl_xor(s2,4); s2 += __shfl_xor(s2,8); s2 += __shfl_xor(s2,16);
    float wn = fmaf(dv * rsqrtf(s2*(1.f/32.f) + EPS), LNg[j], LNb[j]);
    float mx = wn;
    mx = fmaxf(mx, __shfl_xor(mx,1)); mx = fmaxf(mx, __shfl_xor(mx,2)); mx = fmaxf(mx, __shfl_xor(mx,4));
    mx = fmaxf(mx, __shfl_xor(mx,8)); mx = fmaxf(mx, __shfl_xor(mx,16));
    float e = __expf(wn - mx);
    float se = e;
    se += __shfl_xor(se,1); se += __shfl_xor(se,2); se += __shfl_xor(se,4); se += __shfl_xor(se,8); se += __shfl_xor(se,16);
    float wgt = e / se;
    out[OUT_W_OFF + b*NF + j] = wgt;
    wsel[b*NF + j] = wgt;
  }
}

// ---------------- combine: out[t,d] = sum_f w*( (s-mu)*rs*g + b ) ----------------
// block = (blk128, wid, q) slice: 16 tokens x 256 d. Slab reads contiguous per f.
__global__ __launch_bounds__(256) void k_comb(const uint4* __restrict__ stk4,
    const float* __restrict__ muw, const float* __restrict__ rsw,
    const float* __restrict__ wsel, const float* __restrict__ lng, const float* __restrict__ lnb,
    float* __restrict__ out){
  __shared__ float A1L[NF*16];   // w*rs per (f, r)
  __shared__ float MUL[NF*16];   // mu per (f, r)
  __shared__ float wLs[NF];
  __shared__ float obuf[16*256]; // 16 KB f32 transpose buffer
  const int tid = threadIdx.x;
  const int bi = blockIdx.x;
  const int blk = bi>>3, wid = (bi>>1)&3, q = bi&1;
  const int tokw = blk*128 + wid*32;
  const int b = blk>>2;
  if (tid < NF) wLs[tid] = wsel[b*NF + tid];
  for (int e = tid; e < NF*16; e += 256){
    const int fe = e>>4, r = e&15;
    const int m = (r&3) + 8*(r>>2) + 4*q;
    const float rs = rsw[fe*BT + tokw + m];
    A1L[e] = wsel[b*NF + fe] * rs;
    MUL[e] = muw[fe*BT + tokw + m];
  }
  __syncthreads();
  const int U1 = tid + 256;
  const int c0 = tid>>6, j0 = tid&63, col0 = (j0>>1)&31, h0 = j0&1;
  const int c1 = U1>>6,  j1 = U1&63,  col1 = (j1>>1)&31, h1 = j1&1;
  const size_t base = (size_t)blk*4096 + (size_t)(wid*128 + q*64);
  const size_t o0 = base + c0*512 + col0*2 + h0;
  const size_t o1 = base + c1*512 + col1*2 + h1;
  const int d0 = c0*32+col0, d1 = c1*32+col1;
  float acc0[8], acc1[8], accW0 = 0.f, accW1 = 0.f;
  #pragma unroll
  for (int jj=0;jj<8;++jj){ acc0[jj]=0.f; acc1[jj]=0.f; }
  for (int f=0; f<NF; ++f){
    const size_t fo = (size_t)f*262144;
    uint4 v0 = stk4[fo + o0];
    uint4 v1 = stk4[fo + o1];
    float g0 = lng[f*DM+d0], bv0 = lnb[f*DM+d0];
    float g1 = lng[f*DM+d1], bv1 = lnb[f*DM+d1];
    float wf = wLs[f];
    accW0 = fmaf(wf, bv0, accW0);
    accW1 = fmaf(wf, bv1, accW1);
    f16x8 s0 = __builtin_bit_cast(f16x8, v0);
    f16x8 s1 = __builtin_bit_cast(f16x8, v1);
    #pragma unroll
    for (int jj=0;jj<8;++jj){
      float A1 = A1L[f*16 + h0*8 + jj];
      float mu = MUL[f*16 + h0*8 + jj];
      acc0[jj] = fmaf(g0*A1, (float)s0[jj] - mu, acc0[jj]);
    }
    #pragma unroll
    for (int jj=0;jj<8;++jj){
      float A1 = A1L[f*16 + h1*8 + jj];
      float mu = MUL[f*16 + h1*8 + jj];
      acc1[jj] = fmaf(g1*A1, (float)s1[jj] - mu, acc1[jj]);
    }
  }
  #pragma unroll
  for (int jj=0;jj<8;++jj){
    obuf[(h0*8+jj)*256 + d0] = acc0[jj] + accW0;
    obuf[(h1*8+jj)*256 + d1] = acc1[jj] + accW1;
  }
  __syncthreads();
  const float4* ob4 = (const float4*)obuf;
  #pragma unroll
  for (int p=0;p<4;++p){
    int L = tid + 256*p;
    int r = L>>6, rest = L&63;
    int m = (r&3) + 8*(r>>2) + 4*q;
    *(float4*)(out + (size_t)(tokw+m)*DM + rest*4) = ob4[L];
  }
}

extern "C" void kernel_launch(void* const* d_in, const int* in_sizes, int n_in,
                              void* d_out, int out_size, void* d_ws, size_t ws_size,
                              hipStream_t stream) {
  const float* x   = (const float*)d_in[0];
  const float* w1  = (const float*)d_in[1];
  const float* b1  = (const float*)d_in[2];
  const float* w2  = (const float*)d_in[3];
  const float* b2  = (const float*)d_in[4];
  const float* wgm = (const float*)d_in[5];
  const float* bg  = (const float*)d_in[6];
  const float* wsk = (const float*)d_in[7];
  const float* bsk = (const float*)d_in[8];
  const float* lng = (const float*)d_in[9];
  const float* lnb = (const float*)d_in[10];
  const float* W1  = (const float*)d_in[11];
  const float* B1  = (const float*)d_in[12];
  const float* W2  = (const float*)d_in[13];
  const float* B2  = (const float*)d_in[14];
  const float* Wg  = (const float*)d_in[15];
  const float* Bg  = (const float*)d_in[16];
  const float* Wsm = (const float*)d_in[17];
  const float* Bs  = (const float*)d_in[18];
  const float* LNg = (const float*)d_in[19];
  const float* LNb = (const float*)d_in[20];
  float* out = (float*)d_out;

  char* ws = (char*)d_ws;
  uint4* Wpk    = (uint4*)ws;                     // 4 MiB bf16-packed weights
  uint4* stk4   = (uint4*)(ws + 4194304);         // 128 MiB fp16 raw s (MFMA layout)
  float* muw    = (float*)(ws + 138412032);       // 1 MiB
  float* rsw    = (float*)(ws + 139460608);       // 1 MiB
  float* pooled = (float*)(ws + 140509184);       // 512 KiB
  float* hw_pre = (float*)(ws + 141033472);       // 16 KiB
  float* sk_pre = (float*)(ws + 141049856);       // 2 KiB
  float* wsel   = (float*)(ws + 141051904);       // 2 KiB

  (void)hipMemsetAsync(pooled, 0, 524288, stream);
  (void)hipMemsetAsync(hw_pre, 0, 16384 + 2048, stream);

  k_prep<<<dim3(32,8), 256, 0, stream>>>(w2, wgm, Wpk);
  k_pass1<<<dim3(64,32), 256, 0, stream>>>(x, w1, b1, b2, bg, wsk, bsk, lng, lnb,
                                           Wpk, muw, rsw, pooled, stk4);
  k_pass2a<<<dim3(16,16), 256, 0, stream>>>(pooled, W1, Wsm, hw_pre, sk_pre);
  k_pass2b<<<16, 64, 0, stream>>>(hw_pre, sk_pre, B1, W2, B2, Wg, Bg, Bs, LNg, LNb, out, wsel);
  k_comb<<<512, 256, 0, stream>>>(stk4, muw, rsw, wsel, lng, lnb, out);
}